// Round 2
// baseline (503.819 us; speedup 1.0000x reference)
//
#include <hip/hip_runtime.h>
#include <math.h>

// Problem constants (from reference)
#define BATCH 4
#define HW 512
#define NPLANE (512 * 512)
#define NS 12288      // oversampled points per batch
#define NU 3072       // top-k uncertain selected
#define NR 1024       // random extra points
#define NP 4096       // total selected points per batch
#define CF_CH 64
#define CC_CH 128
#define CIN 192
#define HID 256
#define OUTC 4
#define M_TOT (BATCH * NP)  // 16384

// ---------------------------------------------------------------------------
// Bit-exact replication of XLA:CPU's vectorized f32 expf (Cephes polynomial,
// llvm_ir_runtime.cc GenerateVF32Exp), strict per-op f32 rounding, no FMA
// (JAX disables XLA CPU fast-math, so MulAdd = separate mul+add).
// ---------------------------------------------------------------------------
__device__ __forceinline__ float xla_expf(float xin) {
  float x = fminf(fmaxf(xin, -88.3762626647949f), 88.3762626647950f);
  float fx = floorf(__fadd_rn(__fmul_rn(x, 1.44269504088896341f), 0.5f));
  float tmp = __fmul_rn(0.693359375f, fx);
  float z = __fmul_rn(-2.12194440e-4f, fx);
  x = __fsub_rn(__fsub_rn(x, tmp), z);
  float y = __fadd_rn(__fmul_rn(x, 1.9875691500E-4f), 1.3981999507E-3f);
  y = __fadd_rn(__fmul_rn(y, x), 8.3334519073E-3f);
  y = __fadd_rn(__fmul_rn(y, x), 4.1665795894E-2f);
  y = __fadd_rn(__fmul_rn(y, x), 1.6666665459E-1f);
  y = __fadd_rn(__fmul_rn(y, x), 5.0000001201E-1f);
  z = __fmul_rn(x, x);
  y = __fadd_rn(__fmul_rn(y, z), x);
  y = __fadd_rn(y, 1.0f);
  int n = (int)fx;
  float p2n = __int_as_float((n + 127) << 23);
  return __fmul_rn(y, p2n);
}

// ---------------------------------------------------------------------------
// K1: uncertainty at oversampled points, bit-replicating the reference's f32
// chain: per-op rounded bilinear (left-assoc sum), then XLA logistic
// expansion 1/(1+exp(-x)) with the Cephes expf above.
// ---------------------------------------------------------------------------
__global__ void k_uncert(const float* __restrict__ logits,
                         const float* __restrict__ rp,
                         float* __restrict__ u) {
  int gid = blockIdx.x * 256 + threadIdx.x;
  if (gid >= BATCH * NS) return;
  int b = gid / NS;
  float px = rp[(size_t)gid * 2 + 0];
  float py = rp[(size_t)gid * 2 + 1];
  const float* plane = logits + (size_t)b * OUTC * NPLANE;  // channel 0

  float x = __fsub_rn(__fmul_rn(px, 512.0f), 0.5f);
  float y = __fsub_rn(__fmul_rn(py, 512.0f), 0.5f);
  float x0f = floorf(x), y0f = floorf(y);
  float wx = __fsub_rn(x, x0f);
  float wy = __fsub_rn(y, y0f);
  int x0 = (int)x0f, y0 = (int)y0f;
  int x1 = x0 + 1, y1 = y0 + 1;
  bool vx0 = (x0 >= 0) & (x0 < HW);
  bool vx1 = (x1 >= 0) & (x1 < HW);
  bool vy0 = (y0 >= 0) & (y0 < HW);
  bool vy1 = (y1 >= 0) & (y1 < HW);
  float g00 = (vx0 && vy0) ? plane[y0 * HW + x0] : 0.0f;
  float g10 = (vx1 && vy0) ? plane[y0 * HW + x1] : 0.0f;
  float g01 = (vx0 && vy1) ? plane[y1 * HW + x0] : 0.0f;
  float g11 = (vx1 && vy1) ? plane[y1 * HW + x1] : 0.0f;
  float omx = __fsub_rn(1.0f, wx);
  float omy = __fsub_rn(1.0f, wy);
  float w00 = __fmul_rn(omx, omy);
  float w10 = __fmul_rn(wx, omy);
  float w01 = __fmul_rn(omx, wy);
  float w11 = __fmul_rn(wx, wy);
  float s = __fadd_rn(
      __fadd_rn(__fadd_rn(__fmul_rn(g00, w00), __fmul_rn(g10, w10)),
                __fmul_rn(g01, w01)),
      __fmul_rn(g11, w11));
  // sigmoid = 1 / (1 + exp(-s)), each op f32-rounded (XLA logistic expansion)
  float e = xla_expf(-s);
  float sig = __fdiv_rn(1.0f, __fadd_rn(1.0f, e));
  float t = __fmul_rn(fabsf(__fsub_rn(sig, 0.5f)), 2.0f);
  u[gid] = __fsub_rn(1.0f, t);
}

// ---------------------------------------------------------------------------
// K2: exact stable top-k selection via ranking. rank = #{j : u[j]>u[i] or
// (u[j]==u[i] and j<i)}. Selected (rank<NU) point goes to output slot `rank`
// (descending-sorted, stable — matches lax.top_k).
// ---------------------------------------------------------------------------
__global__ __launch_bounds__(256) void k_select(const float* __restrict__ u,
                                                const float* __restrict__ rp,
                                                float* __restrict__ pts_out) {
  __shared__ __align__(16) float su[NS];
  int b = blockIdx.x / (NS / 256);
  int blk = blockIdx.x % (NS / 256);
  const float* ub = u + (size_t)b * NS;
  for (int t = threadIdx.x; t < NS / 4; t += 256)
    ((float4*)su)[t] = ((const float4*)ub)[t];
  __syncthreads();
  int i = blk * 256 + threadIdx.x;
  float ui = su[i];
  int rank = 0;
  for (int j = 0; j < NS; j += 4) {
    float4 v = *(const float4*)&su[j];
    rank += (v.x > ui) || (v.x == ui && (j + 0) < i);
    rank += (v.y > ui) || (v.y == ui && (j + 1) < i);
    rank += (v.z > ui) || (v.z == ui && (j + 2) < i);
    rank += (v.w > ui) || (v.w == ui && (j + 3) < i);
  }
  if (rank < NU) {
    pts_out[((size_t)b * NP + rank) * 2 + 0] = rp[((size_t)b * NS + i) * 2 + 0];
    pts_out[((size_t)b * NP + rank) * 2 + 1] = rp[((size_t)b * NS + i) * 2 + 1];
  }
}

// K2b: append the random-extra points.
__global__ void k_extra(const float* __restrict__ re, float* __restrict__ pts_out) {
  int gid = blockIdx.x * 256 + threadIdx.x;
  if (gid >= BATCH * NR) return;
  int b = gid / NR, j = gid % NR;
  pts_out[((size_t)b * NP + NU + j) * 2 + 0] = re[(size_t)gid * 2 + 0];
  pts_out[((size_t)b * NP + NU + j) * 2 + 1] = re[(size_t)gid * 2 + 1];
}

// ---------------------------------------------------------------------------
// K3: gather 192 feature channels (64 fine + 128 coarse) per point with
// bilinear weights. One wave (64 lanes) per point, 3 channels per lane.
// ---------------------------------------------------------------------------
__global__ __launch_bounds__(256) void k_gather(const float* __restrict__ fine,
                                                const float* __restrict__ coarse,
                                                const float* __restrict__ pts,
                                                float* __restrict__ feats) {
  int gp = blockIdx.x * 4 + (threadIdx.x >> 6);  // global point id [0, 16384)
  int lane = threadIdx.x & 63;
  int b = gp / NP;
  float px = pts[(size_t)gp * 2 + 0];
  float py = pts[(size_t)gp * 2 + 1];
  float x = px * 512.0f - 0.5f;
  float y = py * 512.0f - 0.5f;
  float x0f = floorf(x), y0f = floorf(y);
  float wx = x - x0f, wy = y - y0f;
  int x0 = (int)x0f, y0 = (int)y0f;
  int x1 = x0 + 1, y1 = y0 + 1;
  bool vx0 = (unsigned)x0 < (unsigned)HW;
  bool vx1 = (unsigned)x1 < (unsigned)HW;
  bool vy0 = (unsigned)y0 < (unsigned)HW;
  bool vy1 = (unsigned)y1 < (unsigned)HW;
  float w00 = (1.0f - wx) * (1.0f - wy);
  float w10 = wx * (1.0f - wy);
  float w01 = (1.0f - wx) * wy;
  float w11 = wx * wy;
  const float* fb = fine + (size_t)b * CF_CH * NPLANE;
  const float* cb = coarse + (size_t)b * CC_CH * NPLANE;
  float* frow = feats + (size_t)gp * CIN;
  int i00 = y0 * HW + x0;
#pragma unroll
  for (int cc = 0; cc < 3; ++cc) {
    int c = lane + cc * 64;
    const float* plane =
        (c < CF_CH) ? (fb + (size_t)c * NPLANE) : (cb + (size_t)(c - CF_CH) * NPLANE);
    float g00 = (vx0 && vy0) ? plane[i00] : 0.0f;
    float g10 = (vx1 && vy0) ? plane[i00 + 1] : 0.0f;
    float g01 = (vx0 && vy1) ? plane[i00 + HW] : 0.0f;
    float g11 = (vx1 && vy1) ? plane[i00 + HW + 1] : 0.0f;
    frow[c] = g00 * w00 + g10 * w10 + g01 * w01 + g11 * w11;
  }
}

// ---------------------------------------------------------------------------
// K4/K5: tiled f32 GEMM, C[M][256] = relu(A[M][K] @ W^T + bias), W is [256][K].
// 64x64 tile, BK=32, 256 threads, 4x4 accumulators/thread.
// ---------------------------------------------------------------------------
template <int K>
__global__ __launch_bounds__(256) void k_gemm_relu(const float* __restrict__ A,
                                                   const float* __restrict__ W,
                                                   const float* __restrict__ bias,
                                                   float* __restrict__ C) {
  __shared__ __align__(16) float As[32][68];
  __shared__ __align__(16) float Bs[32][68];
  const int bx = blockIdx.x & 3;   // N tile (256/64)
  const int by = blockIdx.x >> 2;  // M tile
  const int tid = threadIdx.x;
  const int tn = tid & 15, tm = tid >> 4;
  const int m_base = by * 64, n_base = bx * 64;
  float acc[4][4] = {};
  for (int k0 = 0; k0 < K; k0 += 32) {
#pragma unroll
    for (int r = 0; r < 2; ++r) {
      int t = tid + r * 256;
      int row = t >> 3, cg = (t & 7) * 4;
      float4 va = *(const float4*)&A[(size_t)(m_base + row) * K + k0 + cg];
      As[cg + 0][row] = va.x;
      As[cg + 1][row] = va.y;
      As[cg + 2][row] = va.z;
      As[cg + 3][row] = va.w;
      float4 vw = *(const float4*)&W[(size_t)(n_base + row) * K + k0 + cg];
      Bs[cg + 0][row] = vw.x;
      Bs[cg + 1][row] = vw.y;
      Bs[cg + 2][row] = vw.z;
      Bs[cg + 3][row] = vw.w;
    }
    __syncthreads();
#pragma unroll
    for (int kk = 0; kk < 32; ++kk) {
      float4 a4 = *(const float4*)&As[kk][tm * 4];
      float4 b4 = *(const float4*)&Bs[kk][tn * 4];
      float av[4] = {a4.x, a4.y, a4.z, a4.w};
      float bw[4] = {b4.x, b4.y, b4.z, b4.w};
#pragma unroll
      for (int i = 0; i < 4; ++i)
#pragma unroll
        for (int j = 0; j < 4; ++j) acc[i][j] = fmaf(av[i], bw[j], acc[i][j]);
    }
    __syncthreads();
  }
  float bs[4];
#pragma unroll
  for (int j = 0; j < 4; ++j) bs[j] = bias[n_base + tn * 4 + j];
#pragma unroll
  for (int i = 0; i < 4; ++i) {
    float4 o;
    o.x = fmaxf(acc[i][0] + bs[0], 0.0f);
    o.y = fmaxf(acc[i][1] + bs[1], 0.0f);
    o.z = fmaxf(acc[i][2] + bs[2], 0.0f);
    o.w = fmaxf(acc[i][3] + bs[3], 0.0f);
    *(float4*)&C[(size_t)(m_base + tm * 4 + i) * HID + n_base + tn * 4] = o;
  }
}

// ---------------------------------------------------------------------------
// K6: final layer, 4 outputs per point. One wave per point, shuffle reduce.
// out[b][o][n] = h[b*NP+n] . W3[o] + b3[o]
// ---------------------------------------------------------------------------
__global__ __launch_bounds__(256) void k_out(const float* __restrict__ h,
                                             const float* __restrict__ W3,
                                             const float* __restrict__ b3,
                                             float* __restrict__ out) {
  int gp = blockIdx.x * 4 + (threadIdx.x >> 6);
  int lane = threadIdx.x & 63;
  const float* hr = h + (size_t)gp * HID;
  float4 hv = *(const float4*)&hr[lane * 4];
  float s[4];
#pragma unroll
  for (int o = 0; o < 4; ++o) {
    float4 w = *(const float4*)&W3[o * HID + lane * 4];
    s[o] = hv.x * w.x + hv.y * w.y + hv.z * w.z + hv.w * w.w;
  }
#pragma unroll
  for (int off = 32; off; off >>= 1)
#pragma unroll
    for (int o = 0; o < 4; ++o) s[o] += __shfl_xor(s[o], off, 64);
  if (lane == 0) {
    int b = gp / NP, n = gp % NP;
#pragma unroll
    for (int o = 0; o < 4; ++o)
      out[((size_t)b * OUTC + o) * NP + n] = s[o] + b3[o];
  }
}

extern "C" void kernel_launch(void* const* d_in, const int* in_sizes, int n_in,
                              void* d_out, int out_size, void* d_ws, size_t ws_size,
                              hipStream_t stream) {
  const float* fine = (const float*)d_in[0];
  const float* coarse = (const float*)d_in[1];
  const float* logits = (const float*)d_in[2];
  const float* rand_points = (const float*)d_in[3];
  const float* rand_extra = (const float*)d_in[4];
  const float* W1 = (const float*)d_in[5];
  const float* b1 = (const float*)d_in[6];
  const float* W2 = (const float*)d_in[7];
  const float* b2 = (const float*)d_in[8];
  const float* W3 = (const float*)d_in[9];
  const float* b3 = (const float*)d_in[10];
  float* out = (float*)d_out;

  // d_out layout: point_logits [4,4,4096] (65536 f32) then points [4,4096,2]
  float* out_logits = out;
  float* out_points = out + (size_t)BATCH * OUTC * NP;

  // ws layout (no aliasing): u | feats | h1 | h2
  char* ws = (char*)d_ws;
  float* u = (float*)ws;                                   // 192 KiB
  float* feats = (float*)(ws + (1 << 18));                 // 12 MiB
  float* h1 = (float*)(ws + (1 << 18) + (size_t)M_TOT * CIN * 4);
  float* h2 = (float*)(ws + (1 << 18) + (size_t)M_TOT * CIN * 4 +
                       (size_t)M_TOT * HID * 4);

  k_uncert<<<(BATCH * NS + 255) / 256, 256, 0, stream>>>(logits, rand_points, u);
  k_select<<<BATCH * (NS / 256), 256, 0, stream>>>(u, rand_points, out_points);
  k_extra<<<(BATCH * NR + 255) / 256, 256, 0, stream>>>(rand_extra, out_points);
  k_gather<<<M_TOT / 4, 256, 0, stream>>>(fine, coarse, out_points, feats);
  k_gemm_relu<CIN><<<(M_TOT / 64) * 4, 256, 0, stream>>>(feats, W1, b1, h1);
  k_gemm_relu<HID><<<(M_TOT / 64) * 4, 256, 0, stream>>>(h1, W2, b2, h2);
  k_out<<<M_TOT / 4, 256, 0, stream>>>(h2, W3, b3, out_logits);
}